// Round 19
// baseline (254.687 us; speedup 1.0000x reference)
//
#include <hip/hip_runtime.h>

// AxisAttention: x(8,256,128,128) -> per (b,w) sequence over h: QKV GEMM, 4-head
// attention (S=128, d=64), proj GEMM, transposed fp32 output.
// All matmuls: v_mfma_f32_16x16x32_f16, fp32 accum.
// v19 = merge of the two proven k1f halves:
//  - v13's barrier-free A path: wqtf FRAGMENT-MAJOR (one wave A-frag = 1KB
//    contiguous L2 read), A streamed global->reg, NO sA, NO K-loop barriers.
//  - v18's low register pressure: B-frags loaded per-kc (16 VGPR) from the
//    PERSISTENT sXT. Live regs ~85 -> no AGPR banking (v13's 162us failure).
//  LDS = sXT 33792 + sO 17408 = 51200 -> 3 blocks/CU. Barriers/block 62 -> 14.
// k2/k3/prep_w(wpt) byte-identical to v15/v18 (proven).

typedef _Float16 h4 __attribute__((ext_vector_type(4)));
typedef _Float16 h8 __attribute__((ext_vector_type(8)));
typedef float f4 __attribute__((ext_vector_type(4)));
typedef unsigned int u4 __attribute__((ext_vector_type(4)));

#define MFMA32(a, b, c) __builtin_amdgcn_mfma_f32_16x16x32_f16((a), (b), (c), 0, 0, 0)

__device__ __forceinline__ void gll16(const _Float16* g, _Float16* l) {
  __builtin_amdgcn_global_load_lds(
      (const __attribute__((address_space(1))) void*)g,
      (__attribute__((address_space(3))) void*)l, 16, 0, 0);
}

// ---------------- prep: wqtf fragment-major fp16 (v13-proven); wpt[f][c] ------
__global__ __launch_bounds__(256) void prep_w(const float* __restrict__ Wqkv,
                                              const float* __restrict__ Wproj,
                                              _Float16* __restrict__ wqtf,
                                              _Float16* __restrict__ wpt) {
  int i = blockIdx.x * 256 + threadIdx.x;  // 196608 + 65536
  if (i < 768 * 256) {
    int f = i >> 8, c = i & 255;
    // k1f fragment coordinates (v13-proven):
    int ft = f >> 7, wr = (f >> 6) & 1, mt = (f >> 4) & 3, l16 = f & 15;
    int kc = c >> 6, ks = (c >> 5) & 1, gg = (c >> 3) & 3, j = c & 7;
    int frag = (ft * 2 + wr) * 32 + mt * 8 + kc * 2 + ks;
    wqtf[(long)frag * 512 + (gg * 16 + l16) * 8 + j] = (_Float16)Wqkv[c * 768 + f];
  } else {
    int jj = i - 768 * 256;
    int f = jj >> 8, c = jj & 255;
    wpt[jj] = (_Float16)Wproj[c * 256 + f];
  }
}

// ---------------- K1F: fused x-transpose + QKV GEMM (barrier-free K-loop) ------
// Block (bl, hb, wh): tokens t = (w0..w0+63) at fixed h=hb; computes all 768 f.
// Phase 0: coalesced 128B x reads -> sXT[64t][264c] fp16 (PERSISTENT).
// Main: per (ft,kc): 4 B-frags from sXT (LDS), per ks: 4 A-frags streamed from
//       L2-resident wqtf (1KB coalesced), 8 MFMA. Zero barriers in K-loop.
// qkv layout: [qi*nb+bl][head][h][w][d]
__global__ __launch_bounds__(256, 3) void k1f(const float* __restrict__ x,
                                              const _Float16* __restrict__ wqtf,
                                              const float* __restrict__ bqkv,
                                              _Float16* __restrict__ qkv,
                                              int b_base, int nb) {
  const int wg = blockIdx.x;
  const int xcd = wg & 7, seq = wg >> 3;
  const int id = xcd * (nb * 32) + seq;  // bijective: grid = nb*256, %8 == 0
  const int hb = id & 127;
  const int rest = id >> 7;
  const int wh = rest & 1, bl = rest >> 1;
  const int b = b_base + bl;
  const int w0 = wh * 64;

  const int tid = threadIdx.x;
  const int lane = tid & 63, wv = tid >> 6;
  const int g = lane >> 4, l16 = lane & 15;
  const int wr = wv >> 1, wc = wv & 1;  // wave -> (f-half of 128, t-half of 64)

  __shared__ __align__(16) char smem[51200];
  _Float16* sXT = (_Float16*)smem;           // [64 t][264 c] 33792 B, PERSISTENT
  _Float16* sO = (_Float16*)(smem + 33792);  // [64 t][136 f] 17408 B

  // ---- phase 0: transpose x[b][c][hb][w0..w0+63] -> sXT[w][c] (fp16) ----
  {
    const int j0 = tid & 7, r8 = tid >> 3;  // 8 lanes x 16B = 128B coalesced
#pragma unroll
    for (int p = 0; p < 8; ++p) {
      const int c = p * 32 + r8;
      const float* src = x + (((long)b * 256 + c) * 128 + hb) * 128 + w0;
      f4 v0 = *(const f4*)(src + j0 * 4);
      f4 v1 = *(const f4*)(src + (j0 + 8) * 4);
#pragma unroll
      for (int i = 0; i < 4; ++i) {
        sXT[(j0 * 4 + i) * 264 + c] = (_Float16)v0[i];
        sXT[((j0 + 8) * 4 + i) * 264 + c] = (_Float16)v1[i];
      }
    }
  }
  __syncthreads();

  const int wl = tid >> 2, dc = tid & 3;
  const int tB = wc * 32 + l16;  // B-frag token base (nt adds 16)

  // ---- main loop over 6 f-tiles of 128: barrier-free K-loop ----
  for (int ft = 0; ft < 6; ++ft) {
    const int f0 = ft * 128;
    f4 acc[4][2];
#pragma unroll
    for (int mt = 0; mt < 4; ++mt)
#pragma unroll
      for (int nt = 0; nt < 2; ++nt)
#pragma unroll
        for (int r = 0; r < 4; ++r) acc[mt][nt][r] = 0.f;

    // A-fragment base for this (ft, wr): 32 frags x 1KB, lane-coalesced
    const _Float16* Af = wqtf + (long)(ft * 2 + wr) * 32 * 512 + lane * 8;
#pragma unroll
    for (int kc = 0; kc < 4; ++kc) {
      // B-frags for this kc from PERSISTENT sXT (16 VGPR live)
      h8 bfr[2][2];
#pragma unroll
      for (int ks = 0; ks < 2; ++ks)
#pragma unroll
        for (int nt = 0; nt < 2; ++nt)
          bfr[ks][nt] = *(const h8*)(sXT + (tB + nt * 16) * 264 + kc * 64 +
                                     ks * 32 + 8 * g);
#pragma unroll
      for (int ks = 0; ks < 2; ++ks) {
        h8 af[4];
#pragma unroll
        for (int mt = 0; mt < 4; ++mt)
          af[mt] = *(const h8*)(Af + (mt * 8 + kc * 2 + ks) * 512);
#pragma unroll
        for (int mt = 0; mt < 4; ++mt)
#pragma unroll
          for (int nt = 0; nt < 2; ++nt)
            acc[mt][nt] = MFMA32(af[mt], bfr[ks][nt], acc[mt][nt]);
      }
    }

    // epilogue: bias + repack to sO[t][f-local]
#pragma unroll
    for (int mt = 0; mt < 4; ++mt) {
      f4 bb = *(const f4*)(bqkv + f0 + wr * 64 + mt * 16 + 4 * g);
#pragma unroll
      for (int nt = 0; nt < 2; ++nt) {
        const int tl = wc * 32 + nt * 16 + l16;
#pragma unroll
        for (int r = 0; r < 4; ++r)
          sO[tl * 136 + wr * 64 + mt * 16 + 4 * g + r] =
              (_Float16)(acc[mt][nt][r] + bb[r]);
      }
    }
    __syncthreads();
    // store: per (ft,h2) -> one (qi,head): 8KB contiguous
#pragma unroll
    for (int h2 = 0; h2 < 2; ++h2) {
      const int fh = f0 + h2 * 64;
      const int qi = fh >> 8, head = (fh >> 6) & 3;
      _Float16* dst = qkv + (((long)(qi * nb + bl) * 4 + head) * 128 + hb) * 8192 +
                      (w0 + wl) * 64 + dc * 16;
      const _Float16* s = sO + wl * 136 + h2 * 64 + dc * 16;
      *(u4*)dst = *(const u4*)s;
      *(u4*)(dst + 8) = *(const u4*)(s + 8);
    }
    __syncthreads();  // sO reads done before next ft's epilogue overwrites
  }
}

// ---------------- K2: attention per (w, head, bl) ---------------- (v15-proven)
__global__ __launch_bounds__(256) void k2_attn(const _Float16* __restrict__ qkv,
                                               _Float16* __restrict__ attnout,
                                               int nb) {
  const int w = blockIdx.x, head = blockIdx.y, bl = blockIdx.z;
  const int tid = threadIdx.x;
  const int lane = tid & 63, wv = tid >> 6;
  const int g = lane >> 4, l16 = lane & 15;

  __shared__ __align__(16) char smem[(128 * 72 * 2 + 64 * 136) * 2];  // 54272 B
  _Float16* sQ = (_Float16*)smem;
  _Float16* sK = sQ + 128 * 72;
  _Float16* sVT = sK + 128 * 72;
  _Float16* sP = sQ;
  _Float16* sO = sQ;

  const long base = (((long)bl * 4 + head) * 128) * 8192 + (long)w * 64;
  const long QS = (long)nb * 4 * 128 * 8192;
  const _Float16* qg = qkv + base;
  const _Float16* kg = qkv + base + QS;
  const _Float16* vg = qkv + base + 2 * QS;

#pragma unroll
  for (int i = 0; i < 4; ++i) {
    int u = tid + 256 * i;
    int hh = u >> 3, dq = u & 7;
    *(u4*)(sQ + hh * 72 + dq * 8) = *(const u4*)(qg + (long)hh * 8192 + dq * 8);
    *(u4*)(sK + hh * 72 + dq * 8) = *(const u4*)(kg + (long)hh * 8192 + dq * 8);
  }
  {
    const int hh = tid & 127, dcv = tid >> 7;
#pragma unroll
    for (int jj = 0; jj < 4; ++jj) {
      u4 vv = *(const u4*)(vg + (long)hh * 8192 + dcv * 32 + jj * 8);
      const _Float16* pe = (const _Float16*)&vv;
#pragma unroll
      for (int e = 0; e < 8; ++e)
        sVT[(dcv * 32 + jj * 8 + e) * 136 + hh] = pe[e];
    }
  }
  __syncthreads();

  f4 accS[8][2];
  for (int i = 0; i < 8; ++i)
    for (int jt = 0; jt < 2; ++jt)
      for (int r = 0; r < 4; ++r) accS[i][jt][r] = 0.f;
#pragma unroll
  for (int ks = 0; ks < 2; ++ks) {
    const int k = ks * 32 + 8 * g;
    h8 af[8], bf[2];
#pragma unroll
    for (int i = 0; i < 8; ++i)
      af[i] = *(const h8*)(sK + (i * 16 + l16) * 72 + k);
#pragma unroll
    for (int jt = 0; jt < 2; ++jt)
      bf[jt] = *(const h8*)(sQ + (wv * 32 + jt * 16 + l16) * 72 + k);
#pragma unroll
    for (int i = 0; i < 8; ++i)
#pragma unroll
      for (int jt = 0; jt < 2; ++jt)
        accS[i][jt] = MFMA32(af[i], bf[jt], accS[i][jt]);
  }

  float rinv[2];
#pragma unroll
  for (int jt = 0; jt < 2; ++jt) {
    float m = -1e30f;
    for (int i = 0; i < 8; ++i)
      for (int r = 0; r < 4; ++r) m = fmaxf(m, accS[i][jt][r]);
    m = fmaxf(m, __shfl_xor(m, 16));
    m = fmaxf(m, __shfl_xor(m, 32));
    float s = 0.f;
    for (int i = 0; i < 8; ++i)
      for (int r = 0; r < 4; ++r) {
        float p = __expf((accS[i][jt][r] - m) * 0.125f);
        accS[i][jt][r] = p;
        s += p;
      }
    s += __shfl_xor(s, 16);
    s += __shfl_xor(s, 32);
    rinv[jt] = 1.0f / s;
  }

  __syncthreads();
#pragma unroll
  for (int jt = 0; jt < 2; ++jt) {
    const int hq = wv * 32 + jt * 16 + l16;
#pragma unroll
    for (int i = 0; i < 8; ++i) {
      h4 pv;
      pv[0] = (_Float16)accS[i][jt][0];
      pv[1] = (_Float16)accS[i][jt][1];
      pv[2] = (_Float16)accS[i][jt][2];
      pv[3] = (_Float16)accS[i][jt][3];
      *(h4*)(sP + hq * 136 + i * 16 + 4 * g) = pv;
    }
  }
  __syncthreads();

  f4 accO[4][2];
  for (int mt = 0; mt < 4; ++mt)
    for (int jt = 0; jt < 2; ++jt)
      for (int r = 0; r < 4; ++r) accO[mt][jt][r] = 0.f;
#pragma unroll
  for (int i2 = 0; i2 < 4; ++i2) {
    const int k = i2 * 32 + 8 * g;
    h8 av[4], pb[2];
#pragma unroll
    for (int mt = 0; mt < 4; ++mt)
      av[mt] = *(const h8*)(sVT + (mt * 16 + l16) * 136 + k);
#pragma unroll
    for (int jt = 0; jt < 2; ++jt)
      pb[jt] = *(const h8*)(sP + (wv * 32 + jt * 16 + l16) * 136 + k);
#pragma unroll
    for (int mt = 0; mt < 4; ++mt)
#pragma unroll
      for (int jt = 0; jt < 2; ++jt)
        accO[mt][jt] = MFMA32(av[mt], pb[jt], accO[mt][jt]);
  }

  __syncthreads();
#pragma unroll
  for (int mt = 0; mt < 4; ++mt)
#pragma unroll
    for (int jt = 0; jt < 2; ++jt)
#pragma unroll
      for (int r = 0; r < 4; ++r)
        sO[(wv * 32 + jt * 16 + l16) * 72 + mt * 16 + 4 * g + r] =
            (_Float16)(accO[mt][jt][r] * rinv[jt]);
  __syncthreads();

  const int hh = tid >> 1, d0 = (tid & 1) * 32;
  const _Float16* s = sO + hh * 72 + d0;
  _Float16* dst = attnout + ((long)bl * 16384 + hh * 128 + w) * 256 + head * 64 + d0;
#pragma unroll
  for (int e = 0; e < 4; ++e)
    *(u4*)(dst + e * 8) = *(const u4*)(s + e * 8);
}

// ---------------- K3: out[b][co][t] = Wproj^T[co][c]*attnout[t][c]+bproj --------
// (v14-proven: swizzled A/B staging + reads)
__global__ __launch_bounds__(256, 4) void k3_proj(const _Float16* __restrict__ attnout,
                                                  const _Float16* __restrict__ wpt,
                                                  const float* __restrict__ bproj,
                                                  float* __restrict__ out,
                                                  int b_base, int nb) {
  const int ct = blockIdx.x, tt = blockIdx.y, bl = blockIdx.z;
  const int b = b_base + bl;
  const int tid = threadIdx.x;
  const int lane = tid & 63, wv = tid >> 6;
  const int g = lane >> 4, l16 = lane & 15;
  const int wr = wv >> 1, wc = wv & 1;
  const int co0 = ct * 128;
  const long t0 = (long)tt * 128;

  __shared__ __align__(16) char smem[33792];
  _Float16* sA = (_Float16*)smem;   // [128 co][64]
  _Float16* sB = sA + 128 * 64;     // [128 t][64]
  float* sOut = (float*)smem;       // reuse: [64][132] f32

  f4 acc[4][4];
#pragma unroll
  for (int mt = 0; mt < 4; ++mt)
#pragma unroll
    for (int nt = 0; nt < 4; ++nt)
#pragma unroll
      for (int r = 0; r < 4; ++r) acc[mt][nt][r] = 0.f;

  const _Float16* Ab = wpt + (long)co0 * 256;
  const _Float16* Bb = attnout + ((long)bl * 16384 + t0) * 256;
  const int r0 = wv * 32;
  const int rl = lane >> 3;
  const int chs = ((lane & 7) ^ rl) * 8;  // swizzled source chunk
  const int kx = (l16 & 7) * 8;           // read XOR

  for (int kc = 0; kc < 4; ++kc) {
    const int c0 = kc * 64;
#pragma unroll
    for (int i = 0; i < 4; ++i) {
      const int row = r0 + i * 8 + rl;
      gll16(Ab + (long)row * 256 + c0 + chs, sA + (r0 + i * 8) * 64);
      gll16(Bb + (long)row * 256 + c0 + chs, sB + (r0 + i * 8) * 64);
    }
    __syncthreads();
#pragma unroll
    for (int ks = 0; ks < 2; ++ks) {
      const int kk = (ks * 32 + 8 * g) ^ kx;
      h8 af[4], bf[4];
#pragma unroll
      for (int mt = 0; mt < 4; ++mt)
        af[mt] = *(const h8*)(sA + (wr * 64 + mt * 16 + l16) * 64 + kk);
#pragma unroll
      for (int nt = 0; nt < 4; ++nt)
        bf[nt] = *(const h8*)(sB + (wc * 64 + nt * 16 + l16) * 64 + kk);
#pragma unroll
      for (int mt = 0; mt < 4; ++mt)
#pragma unroll
        for (int nt = 0; nt < 4; ++nt)
          acc[mt][nt] = MFMA32(af[mt], bf[nt], acc[mt][nt]);
    }
    __syncthreads();
  }

#pragma unroll
  for (int h2 = 0; h2 < 2; ++h2) {
    if (h2) __syncthreads();
    if (wr == h2) {
#pragma unroll
      for (int mt = 0; mt < 4; ++mt) {
        f4 bb = *(const f4*)(bproj + co0 + h2 * 64 + mt * 16 + 4 * g);
#pragma unroll
        for (int nt = 0; nt < 4; ++nt)
#pragma unroll
          for (int r = 0; r < 4; ++r)
            sOut[(mt * 16 + 4 * g + r) * 132 + wc * 64 + nt * 16 + l16] =
                acc[mt][nt][r] + bb[r];
      }
    }
    __syncthreads();
    const int row = tid >> 2, seg = (tid & 3) * 32;
    const float* s = sOut + row * 132 + seg;
    float* dst = out + ((long)b * 256 + co0 + h2 * 64 + row) * 16384 + t0 + seg;
#pragma unroll
    for (int e = 0; e < 8; ++e)
      *(f4*)(dst + e * 4) = *(const f4*)(s + e * 4);
  }
}

// ---------------- launch ----------------
extern "C" void kernel_launch(void* const* d_in, const int* in_sizes, int n_in,
                              void* d_out, int out_size, void* d_ws, size_t ws_size,
                              hipStream_t stream) {
  const float* x = (const float*)d_in[0];
  const float* Wqkv = (const float*)d_in[1];
  const float* bqkv = (const float*)d_in[2];
  const float* Wproj = (const float*)d_in[3];
  const float* bproj = (const float*)d_in[4];
  float* out = (float*)d_out;

  char* ws = (char*)d_ws;
  // Layout: [wqtf 384K][wpt 128K][qkv nb*24Mi][attnout nb*8Mi]
  const long WQT = 393216L, WPT = 131072L;
  const long PER_B = 25165824L + 8388608L;
  long nb_l = ((long)ws_size - (WQT + WPT)) / PER_B;
  int nb = nb_l < 1 ? 1 : (nb_l > 8 ? 8 : (int)nb_l);

  _Float16* wqtf = (_Float16*)ws;
  _Float16* wpt = (_Float16*)(ws + WQT);
  _Float16* qkv = (_Float16*)(ws + WQT + WPT);
  _Float16* attnout = (_Float16*)(ws + WQT + WPT + (long)nb * 25165824L);

  prep_w<<<1024, 256, 0, stream>>>(Wqkv, Wproj, wqtf, wpt);

  for (int b0 = 0; b0 < 8; b0 += nb) {
    int nbv = (8 - b0 < nb) ? (8 - b0) : nb;
    k1f<<<nbv * 256, 256, 0, stream>>>(x, wqtf, bqkv, qkv, b0, nbv);
    k2_attn<<<dim3(128, 4, nbv), 256, 0, stream>>>(qkv, attnout, nbv);
    k3_proj<<<dim3(2, 128, nbv), 256, 0, stream>>>(attnout, wpt, bproj, out, b0, nbv);
  }
}

// Round 20
// 221.087 us; speedup vs baseline: 1.1520x; 1.1520x over previous
//
#include <hip/hip_runtime.h>

// AxisAttention: x(8,256,128,128) -> per (b,w) sequence over h: QKV GEMM, 4-head
// attention (S=128, d=64), proj GEMM, transposed fp32 output.
// All matmuls: v_mfma_f32_16x16x32_f16, fp32 accum.
// v20: k1+k2 FUSED into k12 (qkv buffer eliminated, ~400MB traffic removed):
//  - prep_x (v9-proven): x -> xt[bl][w*128+h][c] fp16.
//  - k12 block (head,w,bl): QKV GEMM M=192 (this head's q/k/v f-slices),
//    N=128 tokens (all h at w), K=256. A/B staged per kc via v14-proven
//    swizzled gload_lds; 48 MFMA/wave/barrier. acc[12][2] -> ONE epilogue
//    scatters D-frags (m89 layout) + bias into k2's exact sQ/sK/sVT buffers;
//    then k2's attention code verbatim -> attnout.
//  - k3 (v14-proven) unchanged.

typedef _Float16 h4 __attribute__((ext_vector_type(4)));
typedef _Float16 h8 __attribute__((ext_vector_type(8)));
typedef float f4 __attribute__((ext_vector_type(4)));
typedef unsigned int u4 __attribute__((ext_vector_type(4)));

#define MFMA32(a, b, c) __builtin_amdgcn_mfma_f32_16x16x32_f16((a), (b), (c), 0, 0, 0)

__device__ __forceinline__ void gll16(const _Float16* g, _Float16* l) {
  __builtin_amdgcn_global_load_lds(
      (const __attribute__((address_space(1))) void*)g,
      (__attribute__((address_space(3))) void*)l, 16, 0, 0);
}

// ---------------- prep: W^T fp16 (wqt[f][c], wpt[f][c]) ----------------
__global__ __launch_bounds__(256) void prep_w(const float* __restrict__ Wqkv,
                                              const float* __restrict__ Wproj,
                                              _Float16* __restrict__ wqt,
                                              _Float16* __restrict__ wpt) {
  int i = blockIdx.x * 256 + threadIdx.x;  // 196608 + 65536
  if (i < 768 * 256) {
    int f = i >> 8, c = i & 255;
    wqt[i] = (_Float16)Wqkv[c * 768 + f];
  } else {
    int j = i - 768 * 256;
    int f = j >> 8, c = j & 255;
    wpt[j] = (_Float16)Wproj[c * 256 + f];
  }
}

// ---------------- prep_x: x[b][c][h][w] fp32 -> xt[bl][w*128+h][c] fp16 --------
// (v9/v10-proven verbatim)
__global__ __launch_bounds__(256) void prep_x(const float* __restrict__ x,
                                              _Float16* __restrict__ xt,
                                              int b_base) {
  const int h = blockIdx.x, bl = blockIdx.y;
  const int b = b_base + bl;
  const int tid = threadIdx.x;
  __shared__ __align__(16) _Float16 sT[256 * 132];  // 67584 B, pitch 132

  const int wj = tid & 31, cg = tid >> 5;
#pragma unroll
  for (int ci = 0; ci < 32; ++ci) {
    const int c = cg * 32 + ci;
    f4 v = *(const f4*)(x + (((long)b * 256 + c) * 128 + h) * 128 + wj * 4);
    h4 o;
    o[0] = (_Float16)v[0]; o[1] = (_Float16)v[1];
    o[2] = (_Float16)v[2]; o[3] = (_Float16)v[3];
    *(h4*)(sT + c * 132 + wj * 4) = o;
  }
  __syncthreads();

#pragma unroll
  for (int tt2 = tid; tt2 < 512; tt2 += 256) {
    const int cb = tt2 & 31, wb = tt2 >> 5;
    h8 r[8];
#pragma unroll
    for (int j = 0; j < 8; ++j)
      r[j] = *(const h8*)(sT + (cb * 8 + j) * 132 + wb * 8);
#pragma unroll
    for (int i = 0; i < 8; ++i) {
      h8 o;
#pragma unroll
      for (int j = 0; j < 8; ++j) o[j] = r[j][i];
      const int w = wb * 8 + i;
      *(h8*)(xt + ((long)bl * 16384 + w * 128 + h) * 256 + cb * 8) = o;
    }
  }
}

// ---------------- K12: fused QKV GEMM + attention per (head, w, bl) ------------
__global__ __launch_bounds__(256) void k12(const _Float16* __restrict__ xt,
                                           const _Float16* __restrict__ wqt,
                                           const float* __restrict__ bqkv,
                                           _Float16* __restrict__ attnout,
                                           int nb) {
  const int wg = blockIdx.x;
  const int xcd = wg & 7, seq = wg >> 3;
  const int id = xcd * (nb * 64) + seq;  // bijective: grid = nb*512, %8 == 0
  const int head = id & 3;
  const int w = (id >> 2) & 127;
  const int bl = id >> 9;

  const int tid = threadIdx.x;
  const int lane = tid & 63, wv = tid >> 6;
  const int g = lane >> 4, l16 = lane & 15;

  __shared__ __align__(16) char smem[54272];
  // staging phase (dead after K-loop):
  _Float16* sA = (_Float16*)smem;              // [192 f][64 c] 24576 B
  _Float16* sB = (_Float16*)(smem + 24576);    // [128 t][64 c] 16384 B
  // attention phase (aliases staging):
  _Float16* sQ = (_Float16*)smem;              // [128 h][72] 18432 B
  _Float16* sK = (_Float16*)(smem + 18432);    // [128 h][72] 18432 B
  _Float16* sVT = (_Float16*)(smem + 36864);   // [64 d][136] 17408 B
  _Float16* sP = sQ;                           // [128 hq][136] 34816 B
  _Float16* sO = sQ;                           // [128 h][72]

  const int rl = lane >> 3;
  const int chs = ((lane & 7) ^ rl) * 8;  // swizzled source chunk (rule #21)
  const int kx = (l16 & 7) * 8;           // read XOR

  // ---- QKV GEMM: M=192, N=128 tokens, K=256 ----
  f4 acc[12][2];
#pragma unroll
  for (int mt = 0; mt < 12; ++mt)
#pragma unroll
    for (int nt = 0; nt < 2; ++nt)
#pragma unroll
      for (int r = 0; r < 4; ++r) acc[mt][nt][r] = 0.f;

  const _Float16* Bx = xt + ((long)bl * 16384 + w * 128) * 256;

  for (int kc = 0; kc < 4; ++kc) {
    const int c0 = kc * 64;
    // stage A: 192 rows; wave stages rows wv*48 + i*8 + rl (6 calls)
#pragma unroll
    for (int i = 0; i < 6; ++i) {
      const int row = wv * 48 + i * 8 + rl;
      const int fglob = (row >> 6) * 256 + head * 64 + (row & 63);
      gll16(wqt + (long)fglob * 256 + c0 + chs, sA + (wv * 48 + i * 8) * 64);
    }
    // stage B: 128 token rows; wave stages rows wv*32 + i*8 + rl (4 calls)
#pragma unroll
    for (int i = 0; i < 4; ++i) {
      const int trow = wv * 32 + i * 8 + rl;
      gll16(Bx + (long)trow * 256 + c0 + chs, sB + (wv * 32 + i * 8) * 64);
    }
    __syncthreads();
#pragma unroll
    for (int ks = 0; ks < 2; ++ks) {
      const int kk = (ks * 32 + 8 * g) ^ kx;
      h8 bf[2];
#pragma unroll
      for (int nt = 0; nt < 2; ++nt)
        bf[nt] = *(const h8*)(sB + (wv * 32 + nt * 16 + l16) * 64 + kk);
#pragma unroll
      for (int mt = 0; mt < 12; ++mt) {
        h8 af = *(const h8*)(sA + (mt * 16 + l16) * 64 + kk);
#pragma unroll
        for (int nt = 0; nt < 2; ++nt)
          acc[mt][nt] = MFMA32(af, bf[nt], acc[mt][nt]);
      }
    }
    __syncthreads();
  }

  // ---- epilogue-1: bias + scatter D-frags into sQ/sK/sVT ----
  // D layout (m89): col=l16 -> token-within-tile, row=4g+r -> f-within-tile.
#pragma unroll
  for (int mt = 0; mt < 12; ++mt) {
    const int qi = mt >> 2;
    f4 bb = *(const f4*)(bqkv + qi * 256 + head * 64 + (mt & 3) * 16 + 4 * g);
#pragma unroll
    for (int nt = 0; nt < 2; ++nt) {
      const int t = wv * 32 + nt * 16 + l16;
#pragma unroll
      for (int r = 0; r < 4; ++r) {
        const int d = (mt & 3) * 16 + 4 * g + r;
        const _Float16 val = (_Float16)(acc[mt][nt][r] + bb[r]);
        if (qi == 0) sQ[t * 72 + d] = val;
        else if (qi == 1) sK[t * 72 + d] = val;
        else sVT[d * 136 + t] = val;
      }
    }
  }
  __syncthreads();

  // ---- attention (k2-proven code verbatim from here) ----
  f4 accS[8][2];
  for (int i = 0; i < 8; ++i)
    for (int jt = 0; jt < 2; ++jt)
      for (int r = 0; r < 4; ++r) accS[i][jt][r] = 0.f;
#pragma unroll
  for (int ks = 0; ks < 2; ++ks) {
    const int k = ks * 32 + 8 * g;
    h8 af[8], bf[2];
#pragma unroll
    for (int i = 0; i < 8; ++i)
      af[i] = *(const h8*)(sK + (i * 16 + l16) * 72 + k);
#pragma unroll
    for (int jt = 0; jt < 2; ++jt)
      bf[jt] = *(const h8*)(sQ + (wv * 32 + jt * 16 + l16) * 72 + k);
#pragma unroll
    for (int i = 0; i < 8; ++i)
#pragma unroll
      for (int jt = 0; jt < 2; ++jt)
        accS[i][jt] = MFMA32(af[i], bf[jt], accS[i][jt]);
  }

  float rinv[2];
#pragma unroll
  for (int jt = 0; jt < 2; ++jt) {
    float m = -1e30f;
    for (int i = 0; i < 8; ++i)
      for (int r = 0; r < 4; ++r) m = fmaxf(m, accS[i][jt][r]);
    m = fmaxf(m, __shfl_xor(m, 16));
    m = fmaxf(m, __shfl_xor(m, 32));
    float s = 0.f;
    for (int i = 0; i < 8; ++i)
      for (int r = 0; r < 4; ++r) {
        float p = __expf((accS[i][jt][r] - m) * 0.125f);
        accS[i][jt][r] = p;
        s += p;
      }
    s += __shfl_xor(s, 16);
    s += __shfl_xor(s, 32);
    rinv[jt] = 1.0f / s;
  }

  __syncthreads();  // done reading sQ/sK
#pragma unroll
  for (int jt = 0; jt < 2; ++jt) {
    const int hq = wv * 32 + jt * 16 + l16;
#pragma unroll
    for (int i = 0; i < 8; ++i) {
      h4 pv;
      pv[0] = (_Float16)accS[i][jt][0];
      pv[1] = (_Float16)accS[i][jt][1];
      pv[2] = (_Float16)accS[i][jt][2];
      pv[3] = (_Float16)accS[i][jt][3];
      *(h4*)(sP + hq * 136 + i * 16 + 4 * g) = pv;
    }
  }
  __syncthreads();

  f4 accO[4][2];
  for (int mt = 0; mt < 4; ++mt)
    for (int jt = 0; jt < 2; ++jt)
      for (int r = 0; r < 4; ++r) accO[mt][jt][r] = 0.f;
#pragma unroll
  for (int i2 = 0; i2 < 4; ++i2) {
    const int k = i2 * 32 + 8 * g;
    h8 av[4], pb[2];
#pragma unroll
    for (int mt = 0; mt < 4; ++mt)
      av[mt] = *(const h8*)(sVT + (mt * 16 + l16) * 136 + k);
#pragma unroll
    for (int jt = 0; jt < 2; ++jt)
      pb[jt] = *(const h8*)(sP + (wv * 32 + jt * 16 + l16) * 136 + k);
#pragma unroll
    for (int mt = 0; mt < 4; ++mt)
#pragma unroll
      for (int jt = 0; jt < 2; ++jt)
        accO[mt][jt] = MFMA32(av[mt], pb[jt], accO[mt][jt]);
  }

  __syncthreads();  // done reading sP
#pragma unroll
  for (int mt = 0; mt < 4; ++mt)
#pragma unroll
    for (int jt = 0; jt < 2; ++jt)
#pragma unroll
      for (int r = 0; r < 4; ++r)
        sO[(wv * 32 + jt * 16 + l16) * 72 + mt * 16 + 4 * g + r] =
            (_Float16)(accO[mt][jt][r] * rinv[jt]);
  __syncthreads();

  const int hh = tid >> 1, d0 = (tid & 1) * 32;
  const _Float16* s = sO + hh * 72 + d0;
  _Float16* dst = attnout + ((long)bl * 16384 + hh * 128 + w) * 256 + head * 64 + d0;
#pragma unroll
  for (int e = 0; e < 4; ++e)
    *(u4*)(dst + e * 8) = *(const u4*)(s + e * 8);
}

// ---------------- K3: out[b][co][t] = Wproj^T[co][c]*attnout[t][c]+bproj --------
// (v14-proven: swizzled A/B staging + reads)
__global__ __launch_bounds__(256, 4) void k3_proj(const _Float16* __restrict__ attnout,
                                                  const _Float16* __restrict__ wpt,
                                                  const float* __restrict__ bproj,
                                                  float* __restrict__ out,
                                                  int b_base, int nb) {
  const int ct = blockIdx.x, tt = blockIdx.y, bl = blockIdx.z;
  const int b = b_base + bl;
  const int tid = threadIdx.x;
  const int lane = tid & 63, wv = tid >> 6;
  const int g = lane >> 4, l16 = lane & 15;
  const int wr = wv >> 1, wc = wv & 1;
  const int co0 = ct * 128;
  const long t0 = (long)tt * 128;

  __shared__ __align__(16) char smem[33792];
  _Float16* sA = (_Float16*)smem;   // [128 co][64]
  _Float16* sB = sA + 128 * 64;     // [128 t][64]
  float* sOut = (float*)smem;       // reuse: [64][132] f32

  f4 acc[4][4];
#pragma unroll
  for (int mt = 0; mt < 4; ++mt)
#pragma unroll
    for (int nt = 0; nt < 4; ++nt)
#pragma unroll
      for (int r = 0; r < 4; ++r) acc[mt][nt][r] = 0.f;

  const _Float16* Ab = wpt + (long)co0 * 256;
  const _Float16* Bb = attnout + ((long)bl * 16384 + t0) * 256;
  const int r0 = wv * 32;
  const int rl = lane >> 3;
  const int chs = ((lane & 7) ^ rl) * 8;
  const int kx = (l16 & 7) * 8;

  for (int kc = 0; kc < 4; ++kc) {
    const int c0 = kc * 64;
#pragma unroll
    for (int i = 0; i < 4; ++i) {
      const int row = r0 + i * 8 + rl;
      gll16(Ab + (long)row * 256 + c0 + chs, sA + (r0 + i * 8) * 64);
      gll16(Bb + (long)row * 256 + c0 + chs, sB + (r0 + i * 8) * 64);
    }
    __syncthreads();
#pragma unroll
    for (int ks = 0; ks < 2; ++ks) {
      const int kk = (ks * 32 + 8 * g) ^ kx;
      h8 af[4], bf[4];
#pragma unroll
      for (int mt = 0; mt < 4; ++mt)
        af[mt] = *(const h8*)(sA + (wr * 64 + mt * 16 + l16) * 64 + kk);
#pragma unroll
      for (int nt = 0; nt < 4; ++nt)
        bf[nt] = *(const h8*)(sB + (wc * 64 + nt * 16 + l16) * 64 + kk);
#pragma unroll
      for (int mt = 0; mt < 4; ++mt)
#pragma unroll
        for (int nt = 0; nt < 4; ++nt)
          acc[mt][nt] = MFMA32(af[mt], bf[nt], acc[mt][nt]);
    }
    __syncthreads();
  }

#pragma unroll
  for (int h2 = 0; h2 < 2; ++h2) {
    if (h2) __syncthreads();
    if (wr == h2) {
#pragma unroll
      for (int mt = 0; mt < 4; ++mt) {
        f4 bb = *(const f4*)(bproj + co0 + h2 * 64 + mt * 16 + 4 * g);
#pragma unroll
        for (int nt = 0; nt < 4; ++nt)
#pragma unroll
          for (int r = 0; r < 4; ++r)
            sOut[(mt * 16 + 4 * g + r) * 132 + wc * 64 + nt * 16 + l16] =
                acc[mt][nt][r] + bb[r];
      }
    }
    __syncthreads();
    const int row = tid >> 2, seg = (tid & 3) * 32;
    const float* s = sOut + row * 132 + seg;
    float* dst = out + ((long)b * 256 + co0 + h2 * 64 + row) * 16384 + t0 + seg;
#pragma unroll
    for (int e = 0; e < 8; ++e)
      *(f4*)(dst + e * 4) = *(const f4*)(s + e * 4);
  }
}

// ---------------- launch ----------------
extern "C" void kernel_launch(void* const* d_in, const int* in_sizes, int n_in,
                              void* d_out, int out_size, void* d_ws, size_t ws_size,
                              hipStream_t stream) {
  const float* x = (const float*)d_in[0];
  const float* Wqkv = (const float*)d_in[1];
  const float* bqkv = (const float*)d_in[2];
  const float* Wproj = (const float*)d_in[3];
  const float* bproj = (const float*)d_in[4];
  float* out = (float*)d_out;

  char* ws = (char*)d_ws;
  // Layout: [wqt 384K][wpt 128K][xt nb*8Mi][attnout nb*8Mi]  (no qkv buffer)
  const long WQT = 393216L, WPT = 131072L;
  const long PER_B = 8388608L + 8388608L;
  long nb_l = ((long)ws_size - (WQT + WPT)) / PER_B;
  int nb = nb_l < 1 ? 1 : (nb_l > 8 ? 8 : (int)nb_l);

  _Float16* wqt = (_Float16*)ws;
  _Float16* wpt = (_Float16*)(ws + WQT);
  _Float16* xt = (_Float16*)(ws + WQT + WPT);
  _Float16* attnout = (_Float16*)(ws + WQT + WPT + (long)nb * 8388608L);

  prep_w<<<1024, 256, 0, stream>>>(Wqkv, Wproj, wqt, wpt);

  for (int b0 = 0; b0 < 8; b0 += nb) {
    int nbv = (8 - b0 < nb) ? (8 - b0) : nb;
    prep_x<<<dim3(128, nbv), 256, 0, stream>>>(x, xt, b0);
    k12<<<nbv * 512, 256, 0, stream>>>(xt, wqt, bqkv, attnout, nbv);
    k3_proj<<<dim3(2, 128, nbv), 256, 0, stream>>>(attnout, wpt, bproj, out, b0, nbv);
  }
}

// Round 21
// 205.658 us; speedup vs baseline: 1.2384x; 1.0750x over previous
//
#include <hip/hip_runtime.h>

// AxisAttention: x(8,256,128,128) -> per (b,w) sequence over h: QKV GEMM, 4-head
// attention (S=128, d=64), proj GEMM, transposed fp32 output.
// All matmuls: v_mfma_f32_16x16x32_f16, fp32 accum.
// v21 = v20 with k12's attention LDS shrunk 54272 -> 49152 (3 blocks/CU):
//   sQ/sK [128][64] + chunk-XOR (d>>3)^(t&7); sVT [64][128] + (t>>3)^(d&7);
//   sP [128][128] + (hk>>3)^(hq&7), aliasing sQ+sK. Same involution on write
//   (epilogue scatter / P-store) and read (QK^T / PV fragments) — pure-LDS
//   both-sides swizzle (k3-proven pattern). Q/K scatter now h4-vectorized.
// prep_x / prep_w / k3 byte-identical to v20 (proven).

typedef _Float16 h4 __attribute__((ext_vector_type(4)));
typedef _Float16 h8 __attribute__((ext_vector_type(8)));
typedef float f4 __attribute__((ext_vector_type(4)));
typedef unsigned int u4 __attribute__((ext_vector_type(4)));

#define MFMA32(a, b, c) __builtin_amdgcn_mfma_f32_16x16x32_f16((a), (b), (c), 0, 0, 0)

__device__ __forceinline__ void gll16(const _Float16* g, _Float16* l) {
  __builtin_amdgcn_global_load_lds(
      (const __attribute__((address_space(1))) void*)g,
      (__attribute__((address_space(3))) void*)l, 16, 0, 0);
}

// ---------------- prep: W^T fp16 (wqt[f][c], wpt[f][c]) ----------------
__global__ __launch_bounds__(256) void prep_w(const float* __restrict__ Wqkv,
                                              const float* __restrict__ Wproj,
                                              _Float16* __restrict__ wqt,
                                              _Float16* __restrict__ wpt) {
  int i = blockIdx.x * 256 + threadIdx.x;  // 196608 + 65536
  if (i < 768 * 256) {
    int f = i >> 8, c = i & 255;
    wqt[i] = (_Float16)Wqkv[c * 768 + f];
  } else {
    int j = i - 768 * 256;
    int f = j >> 8, c = j & 255;
    wpt[j] = (_Float16)Wproj[c * 256 + f];
  }
}

// ---------------- prep_x: x[b][c][h][w] fp32 -> xt[bl][w*128+h][c] fp16 --------
__global__ __launch_bounds__(256) void prep_x(const float* __restrict__ x,
                                              _Float16* __restrict__ xt,
                                              int b_base) {
  const int h = blockIdx.x, bl = blockIdx.y;
  const int b = b_base + bl;
  const int tid = threadIdx.x;
  __shared__ __align__(16) _Float16 sT[256 * 132];  // 67584 B

  const int wj = tid & 31, cg = tid >> 5;
#pragma unroll
  for (int ci = 0; ci < 32; ++ci) {
    const int c = cg * 32 + ci;
    f4 v = *(const f4*)(x + (((long)b * 256 + c) * 128 + h) * 128 + wj * 4);
    h4 o;
    o[0] = (_Float16)v[0]; o[1] = (_Float16)v[1];
    o[2] = (_Float16)v[2]; o[3] = (_Float16)v[3];
    *(h4*)(sT + c * 132 + wj * 4) = o;
  }
  __syncthreads();

#pragma unroll
  for (int tt2 = tid; tt2 < 512; tt2 += 256) {
    const int cb = tt2 & 31, wb = tt2 >> 5;
    h8 r[8];
#pragma unroll
    for (int j = 0; j < 8; ++j)
      r[j] = *(const h8*)(sT + (cb * 8 + j) * 132 + wb * 8);
#pragma unroll
    for (int i = 0; i < 8; ++i) {
      h8 o;
#pragma unroll
      for (int j = 0; j < 8; ++j) o[j] = r[j][i];
      const int w = wb * 8 + i;
      *(h8*)(xt + ((long)bl * 16384 + w * 128 + h) * 256 + cb * 8) = o;
    }
  }
}

// ---------------- K12: fused QKV GEMM + attention per (head, w, bl) ------------
__global__ __launch_bounds__(256, 3) void k12(const _Float16* __restrict__ xt,
                                              const _Float16* __restrict__ wqt,
                                              const float* __restrict__ bqkv,
                                              _Float16* __restrict__ attnout,
                                              int nb) {
  const int wg = blockIdx.x;
  const int xcd = wg & 7, seq = wg >> 3;
  const int id = xcd * (nb * 64) + seq;  // bijective: grid = nb*512, %8 == 0
  const int head = id & 3;
  const int w = (id >> 2) & 127;
  const int bl = id >> 9;

  const int tid = threadIdx.x;
  const int lane = tid & 63, wv = tid >> 6;
  const int g = lane >> 4, l16 = lane & 15;

  __shared__ __align__(16) char smem[49152];
  // staging phase (dead after K-loop):
  _Float16* sA = (_Float16*)smem;              // [192 f][64 c] 24576 B
  _Float16* sB = (_Float16*)(smem + 24576);    // [128 t][64 c] 16384 B
  // attention phase (aliases staging), ALL chunk-XOR swizzled, unpadded:
  _Float16* sQ = (_Float16*)smem;              // [128 t][64 d] 16384 B
  _Float16* sK = (_Float16*)(smem + 16384);    // [128 t][64 d] 16384 B
  _Float16* sVT = (_Float16*)(smem + 32768);   // [64 d][128 t] 16384 B
  _Float16* sP = sQ;                           // [128 hq][128 hk] 32768 B
  _Float16* sO = sQ;                           // [128 h][72] 18432 B

  const int rl = lane >> 3;
  const int chs = ((lane & 7) ^ rl) * 8;  // swizzled gload source chunk
  const int kx7 = l16 & 7;                // row-parity for LDS read XOR

  // ---- QKV GEMM: M=192, N=128 tokens, K=256 ----
  f4 acc[12][2];
#pragma unroll
  for (int mt = 0; mt < 12; ++mt)
#pragma unroll
    for (int nt = 0; nt < 2; ++nt)
#pragma unroll
      for (int r = 0; r < 4; ++r) acc[mt][nt][r] = 0.f;

  const _Float16* Bx = xt + ((long)bl * 16384 + w * 128) * 256;

  for (int kc = 0; kc < 4; ++kc) {
    const int c0 = kc * 64;
#pragma unroll
    for (int i = 0; i < 6; ++i) {
      const int row = wv * 48 + i * 8 + rl;
      const int fglob = (row >> 6) * 256 + head * 64 + (row & 63);
      gll16(wqt + (long)fglob * 256 + c0 + chs, sA + (wv * 48 + i * 8) * 64);
    }
#pragma unroll
    for (int i = 0; i < 4; ++i) {
      const int trow = wv * 32 + i * 8 + rl;
      gll16(Bx + (long)trow * 256 + c0 + chs, sB + (wv * 32 + i * 8) * 64);
    }
    __syncthreads();
#pragma unroll
    for (int ks = 0; ks < 2; ++ks) {
      const int kk = ((ks * 4 + g) ^ kx7) * 8;
      h8 bf[2];
#pragma unroll
      for (int nt = 0; nt < 2; ++nt)
        bf[nt] = *(const h8*)(sB + (wv * 32 + nt * 16 + l16) * 64 + kk);
#pragma unroll
      for (int mt = 0; mt < 12; ++mt) {
        h8 af = *(const h8*)(sA + (mt * 16 + l16) * 64 + kk);
#pragma unroll
        for (int nt = 0; nt < 2; ++nt)
          acc[mt][nt] = MFMA32(af, bf[nt], acc[mt][nt]);
      }
    }
    __syncthreads();
  }

  // ---- epilogue-1: bias + scatter D-frags into swizzled sQ/sK/sVT ----
  // D layout (m89): col=l16 -> token-in-tile, row=4g+r -> f-in-tile.
#pragma unroll
  for (int mt = 0; mt < 12; ++mt) {
    const int qi = mt >> 2;
    f4 bb = *(const f4*)(bqkv + qi * 256 + head * 64 + (mt & 3) * 16 + 4 * g);
#pragma unroll
    for (int nt = 0; nt < 2; ++nt) {
      const int t = wv * 32 + nt * 16 + l16;
      if (qi < 2) {
        // Q/K: element (t, d); chunk (d>>3)^(t&7); h4 at in-chunk offset 4(g&1)
        h4 pv;
#pragma unroll
        for (int r = 0; r < 4; ++r) pv[r] = (_Float16)(acc[mt][nt][r] + bb[r]);
        const int c8 = ((mt & 3) * 2 + (g >> 1)) ^ (t & 7);
        _Float16* base = (qi == 0 ? sQ : sK);
        *(h4*)(base + t * 64 + c8 * 8 + 4 * (g & 1)) = pv;
      } else {
        // V^T: element (d, t); chunk (t>>3)^(d&7), offset t&7 (scalar)
#pragma unroll
        for (int r = 0; r < 4; ++r) {
          const int d = (mt & 3) * 16 + 4 * g + r;
          sVT[d * 128 + (((t >> 3) ^ (d & 7)) * 8) + (t & 7)] =
              (_Float16)(acc[mt][nt][r] + bb[r]);
        }
      }
    }
  }
  __syncthreads();

  // ---- attention: S^T = K * Q^T ----
  f4 accS[8][2];
  for (int i = 0; i < 8; ++i)
    for (int jt = 0; jt < 2; ++jt)
      for (int r = 0; r < 4; ++r) accS[i][jt][r] = 0.f;
#pragma unroll
  for (int ks = 0; ks < 2; ++ks) {
    const int kk = ((ks * 4 + g) ^ kx7) * 8;
    h8 af[8], bf[2];
#pragma unroll
    for (int i = 0; i < 8; ++i)
      af[i] = *(const h8*)(sK + (i * 16 + l16) * 64 + kk);
#pragma unroll
    for (int jt = 0; jt < 2; ++jt)
      bf[jt] = *(const h8*)(sQ + (wv * 32 + jt * 16 + l16) * 64 + kk);
#pragma unroll
    for (int i = 0; i < 8; ++i)
#pragma unroll
      for (int jt = 0; jt < 2; ++jt)
        accS[i][jt] = MFMA32(af[i], bf[jt], accS[i][jt]);
  }

  float rinv[2];
#pragma unroll
  for (int jt = 0; jt < 2; ++jt) {
    float m = -1e30f;
    for (int i = 0; i < 8; ++i)
      for (int r = 0; r < 4; ++r) m = fmaxf(m, accS[i][jt][r]);
    m = fmaxf(m, __shfl_xor(m, 16));
    m = fmaxf(m, __shfl_xor(m, 32));
    float s = 0.f;
    for (int i = 0; i < 8; ++i)
      for (int r = 0; r < 4; ++r) {
        float p = __expf((accS[i][jt][r] - m) * 0.125f);
        accS[i][jt][r] = p;
        s += p;
      }
    s += __shfl_xor(s, 16);
    s += __shfl_xor(s, 32);
    rinv[jt] = 1.0f / s;
  }

  __syncthreads();  // done reading sQ/sK
  // write P (unnorm) to swizzled sP: element (hq, hk); chunk (hk>>3)^(hq&7)
#pragma unroll
  for (int jt = 0; jt < 2; ++jt) {
    const int hq = wv * 32 + jt * 16 + l16;
#pragma unroll
    for (int i = 0; i < 8; ++i) {
      h4 pv;
      pv[0] = (_Float16)accS[i][jt][0];
      pv[1] = (_Float16)accS[i][jt][1];
      pv[2] = (_Float16)accS[i][jt][2];
      pv[3] = (_Float16)accS[i][jt][3];
      const int c8 = (i * 2 + (g >> 1)) ^ (hq & 7);
      *(h4*)(sP + hq * 128 + c8 * 8 + 4 * (g & 1)) = pv;
    }
  }
  __syncthreads();

  // O^T[d][hq] = V^T * P^T, K = 128
  f4 accO[4][2];
  for (int mt = 0; mt < 4; ++mt)
    for (int jt = 0; jt < 2; ++jt)
      for (int r = 0; r < 4; ++r) accO[mt][jt][r] = 0.f;
#pragma unroll
  for (int i2 = 0; i2 < 4; ++i2) {
    const int kk = ((i2 * 4 + g) ^ kx7) * 8;
    h8 av[4], pb[2];
#pragma unroll
    for (int mt = 0; mt < 4; ++mt)
      av[mt] = *(const h8*)(sVT + (mt * 16 + l16) * 128 + kk);
#pragma unroll
    for (int jt = 0; jt < 2; ++jt)
      pb[jt] = *(const h8*)(sP + (wv * 32 + jt * 16 + l16) * 128 + kk);
#pragma unroll
    for (int mt = 0; mt < 4; ++mt)
#pragma unroll
      for (int jt = 0; jt < 2; ++jt)
        accO[mt][jt] = MFMA32(av[mt], pb[jt], accO[mt][jt]);
  }

  __syncthreads();  // done reading sP
#pragma unroll
  for (int mt = 0; mt < 4; ++mt)
#pragma unroll
    for (int jt = 0; jt < 2; ++jt)
#pragma unroll
      for (int r = 0; r < 4; ++r)
        sO[(wv * 32 + jt * 16 + l16) * 72 + mt * 16 + 4 * g + r] =
            (_Float16)(accO[mt][jt][r] * rinv[jt]);
  __syncthreads();

  const int hh = tid >> 1, d0 = (tid & 1) * 32;
  const _Float16* s = sO + hh * 72 + d0;
  _Float16* dst = attnout + ((long)bl * 16384 + hh * 128 + w) * 256 + head * 64 + d0;
#pragma unroll
  for (int e = 0; e < 4; ++e)
    *(u4*)(dst + e * 8) = *(const u4*)(s + e * 8);
}

// ---------------- K3: out[b][co][t] = Wproj^T[co][c]*attnout[t][c]+bproj --------
// (v14-proven)
__global__ __launch_bounds__(256, 4) void k3_proj(const _Float16* __restrict__ attnout,
                                                  const _Float16* __restrict__ wpt,
                                                  const float* __restrict__ bproj,
                                                  float* __restrict__ out,
                                                  int b_base, int nb) {
  const int ct = blockIdx.x, tt = blockIdx.y, bl = blockIdx.z;
  const int b = b_base + bl;
  const int tid = threadIdx.x;
  const int lane = tid & 63, wv = tid >> 6;
  const int g = lane >> 4, l16 = lane & 15;
  const int wr = wv >> 1, wc = wv & 1;
  const int co0 = ct * 128;
  const long t0 = (long)tt * 128;

  __shared__ __align__(16) char smem[33792];
  _Float16* sA = (_Float16*)smem;   // [128 co][64]
  _Float16* sB = sA + 128 * 64;     // [128 t][64]
  float* sOut = (float*)smem;       // reuse: [64][132] f32

  f4 acc[4][4];
#pragma unroll
  for (int mt = 0; mt < 4; ++mt)
#pragma unroll
    for (int nt = 0; nt < 4; ++nt)
#pragma unroll
      for (int r = 0; r < 4; ++r) acc[mt][nt][r] = 0.f;

  const _Float16* Ab = wpt + (long)co0 * 256;
  const _Float16* Bb = attnout + ((long)bl * 16384 + t0) * 256;
  const int r0 = wv * 32;
  const int rl = lane >> 3;
  const int chs = ((lane & 7) ^ rl) * 8;
  const int kx = (l16 & 7) * 8;

  for (int kc = 0; kc < 4; ++kc) {
    const int c0 = kc * 64;
#pragma unroll
    for (int i = 0; i < 4; ++i) {
      const int row = r0 + i * 8 + rl;
      gll16(Ab + (long)row * 256 + c0 + chs, sA + (r0 + i * 8) * 64);
      gll16(Bb + (long)row * 256 + c0 + chs, sB + (r0 + i * 8) * 64);
    }
    __syncthreads();
#pragma unroll
    for (int ks = 0; ks < 2; ++ks) {
      const int kk = (ks * 32 + 8 * g) ^ kx;
      h8 af[4], bf[4];
#pragma unroll
      for (int mt = 0; mt < 4; ++mt)
        af[mt] = *(const h8*)(sA + (wr * 64 + mt * 16 + l16) * 64 + kk);
#pragma unroll
      for (int nt = 0; nt < 4; ++nt)
        bf[nt] = *(const h8*)(sB + (wc * 64 + nt * 16 + l16) * 64 + kk);
#pragma unroll
      for (int mt = 0; mt < 4; ++mt)
#pragma unroll
        for (int nt = 0; nt < 4; ++nt)
          acc[mt][nt] = MFMA32(af[mt], bf[nt], acc[mt][nt]);
    }
    __syncthreads();
  }

#pragma unroll
  for (int h2 = 0; h2 < 2; ++h2) {
    if (h2) __syncthreads();
    if (wr == h2) {
#pragma unroll
      for (int mt = 0; mt < 4; ++mt) {
        f4 bb = *(const f4*)(bproj + co0 + h2 * 64 + mt * 16 + 4 * g);
#pragma unroll
        for (int nt = 0; nt < 4; ++nt)
#pragma unroll
          for (int r = 0; r < 4; ++r)
            sOut[(mt * 16 + 4 * g + r) * 132 + wc * 64 + nt * 16 + l16] =
                acc[mt][nt][r] + bb[r];
      }
    }
    __syncthreads();
    const int row = tid >> 2, seg = (tid & 3) * 32;
    const float* s = sOut + row * 132 + seg;
    float* dst = out + ((long)b * 256 + co0 + h2 * 64 + row) * 16384 + t0 + seg;
#pragma unroll
    for (int e = 0; e < 8; ++e)
      *(f4*)(dst + e * 4) = *(const f4*)(s + e * 4);
  }
}

// ---------------- launch ----------------
extern "C" void kernel_launch(void* const* d_in, const int* in_sizes, int n_in,
                              void* d_out, int out_size, void* d_ws, size_t ws_size,
                              hipStream_t stream) {
  const float* x = (const float*)d_in[0];
  const float* Wqkv = (const float*)d_in[1];
  const float* bqkv = (const float*)d_in[2];
  const float* Wproj = (const float*)d_in[3];
  const float* bproj = (const float*)d_in[4];
  float* out = (float*)d_out;

  char* ws = (char*)d_ws;
  // Layout: [wqt 384K][wpt 128K][xt nb*8Mi][attnout nb*8Mi]
  const long WQT = 393216L, WPT = 131072L;
  const long PER_B = 8388608L + 8388608L;
  long nb_l = ((long)ws_size - (WQT + WPT)) / PER_B;
  int nb = nb_l < 1 ? 1 : (nb_l > 8 ? 8 : (int)nb_l);

  _Float16* wqt = (_Float16*)ws;
  _Float16* wpt = (_Float16*)(ws + WQT);
  _Float16* xt = (_Float16*)(ws + WQT + WPT);
  _Float16* attnout = (_Float16*)(ws + WQT + WPT + (long)nb * 8388608L);

  prep_w<<<1024, 256, 0, stream>>>(Wqkv, Wproj, wqt, wpt);

  for (int b0 = 0; b0 < 8; b0 += nb) {
    int nbv = (8 - b0 < nb) ? (8 - b0) : nb;
    prep_x<<<dim3(128, nbv), 256, 0, stream>>>(x, xt, b0);
    k12<<<nbv * 512, 256, 0, stream>>>(xt, wqt, bqkv, attnout, nbv);
    k3_proj<<<dim3(2, 128, nbv), 256, 0, stream>>>(attnout, wpt, bproj, out, b0, nbv);
  }
}